// Round 14
// baseline (144.807 us; speedup 1.0000x reference)
//
#include <hip/hip_runtime.h>
#include <math.h>

#define HH 28
#define WW 28
#define NPIX 784
#define MMAX 785
#define NMAXP 100
#define NTH 512
#define BCAP 512       // max basins (theory bound: H1 4-conn <= 393)
#define HSZ 2048
#define HMASK 2047
#define ECAP 2048      // deduped basin-pair edges (random ~470); max survivors = HSZ
#define PCAP 512
#define JMAXP 10       // 2^10 >= 785 worst-case descent depth
// Essential-death sentinel: must stay FINITE after the harness's bf16
// round-trip (FLT_MAX rounds to +inf in bf16 -> inf-inf=NaN). 1e30 is safe.
#define ESS_DEATH 1e30f

template<int N> struct IC { static constexpr int v = N; };

// monotone float<->u32 (totally ordered as unsigned)
__device__ __forceinline__ unsigned f2mono(float f) {
    unsigned u = __float_as_uint(f);
    return (u & 0x80000000u) ? ~u : (u | 0x80000000u);
}
__device__ __forceinline__ float mono2f(unsigned m) {
    unsigned u = (m & 0x80000000u) ? (m ^ 0x80000000u) : ~m;
    return __uint_as_float(u);
}

// neighbors of cell c; nb[k] = -1 if invalid.
// which==0: 8-conn. which==1: 4-conn + virtual boundary node NPIX.
__device__ __forceinline__ int get_nbrs(int c, int which, int* nb) {
    int ci = c / WW;
    int cj = c - ci * WW;
    if (which == 0) {
        const int di[8] = {-1,-1,-1, 0, 0, 1, 1, 1};
        const int dj[8] = {-1, 0, 1,-1, 1,-1, 0, 1};
        #pragma unroll
        for (int k = 0; k < 8; ++k) {
            int ii = ci + di[k], jj = cj + dj[k];
            nb[k] = (ii >= 0 && ii < HH && jj >= 0 && jj < WW) ? (ii * WW + jj) : -1;
        }
        return 8;
    } else {
        const int di[4] = {-1, 1, 0, 0};
        const int dj[4] = { 0, 0,-1, 1};
        #pragma unroll
        for (int k = 0; k < 4; ++k) {
            int ii = ci + di[k], jj = cj + dj[k];
            nb[k] = (ii >= 0 && ii < HH && jj >= 0 && jj < WW) ? (ii * WW + jj) : -1;
        }
        nb[4] = (ci == 0 || ci == HH - 1 || cj == 0 || cj == WW - 1) ? NPIX : -1;
        return 5;
    }
}

// One block per (sample, dim): blk = s*2 + which.
// which==0 -> H0 (8-conn sublevel on x); which==1 -> H1 via superlevel
// (sublevel on -x, 4-conn, virtual -inf boundary node).
__global__ __launch_bounds__(NTH)
void pd_kernel(const float* __restrict__ x, float* __restrict__ out)
{
    const int blk   = blockIdx.x;
    const int s     = blk >> 1;
    const int which = blk & 1;
    const int tid   = threadIdx.x;
    const int lane  = tid & 63;
    const int M     = NPIX + which;

    __shared__ float vals[MMAX];
    __shared__ int   dA[MMAX];                  // steepest-descent pointer (ping)
    __shared__ int   dB[MMAX];                  // pointer (pong)
    __shared__ int   cido[MMAX];                // per-cell compact basin id
    __shared__ unsigned long long rootsU[BCAP]; // unsorted (valmono<<32)|cell, 64-padded
    __shared__ unsigned bval[BCAP];             // basin-min valmono per cid (= value rank)
    __shared__ unsigned hkey[HSZ];              // hash: pk+1 (0 = empty)
    __shared__ unsigned hval[HSZ];              // hash: min weight (monotone u32)
    __shared__ unsigned long long e2[ECAP];     // unsorted (wmono<<18)|pk; later sel keys
    __shared__ unsigned long long e3[ECAP];     // rank-scattered edges (weight order)
    __shared__ unsigned long long mrec[PCAP + 1]; // raw merges (wmono<<32)|y; [PCAP]=dump
    __shared__ float pb[PCAP], pdd[PCAP];       // recorded pairs (output space)
    __shared__ int   rsel[NMAXP];               // output slot -> pair index
    __shared__ int   bcnt, scnt, npairs;
    __shared__ int   jflag[JMAXP + 1];

    // rank of ki among arr[0..N64) (N64 = 64-multiple, padded with ~0ull;
    // distinct keys). Chunked: wave loads 64 keys coalesced, broadcasts via
    // readlane (unrolled -> constant lane), counts kjj < ki. No barriers.
    auto rankOf = [&](const unsigned long long* arr, int N64,
                      unsigned long long ki) -> int {
        int rk = 0;
        for (int base = 0; base < N64; base += 64) {
            unsigned long long kj = arr[base + lane];
            unsigned lo = (unsigned)kj, hi = (unsigned)(kj >> 32);
            #pragma unroll
            for (int t = 0; t < 64; ++t) {
                unsigned jlo = (unsigned)__builtin_amdgcn_readlane((int)lo, t);
                unsigned jhi = (unsigned)__builtin_amdgcn_readlane((int)hi, t);
                unsigned long long kjj = ((unsigned long long)jhi << 32) | jlo;
                rk += (kjj < ki) ? 1 : 0;
            }
        }
        return rk;
    };

    if (tid == 0) { bcnt = 0; scnt = 0; npairs = 0; }
    if (tid < JMAXP + 1) jflag[tid] = 0;
    for (int i = tid; i < HSZ; i += NTH) { hkey[i] = 0u; hval[i] = 0xFFFFFFFFu; }
    for (int i = tid; i < NPIX; i += NTH) {
        float v = x[s * NPIX + i];
        vals[i] = which ? -v : v;
    }
    if (tid == 0 && which) vals[NPIX] = -INFINITY;
    __syncthreads();

    // ---- steepest-descent pointer: lex-min (val, idx) over {self} U nbrs ----
    for (int i = tid; i < M; i += NTH) {
        int best = i; float bv = vals[i];
        if (i < NPIX) {
            int nb[8];
            int K = get_nbrs(i, which, nb);
            for (int k = 0; k < K; ++k) {
                int n = nb[k]; if (n < 0) continue;
                float vn = vals[n];
                if (vn < bv || (vn == bv && n < best)) { bv = vn; best = n; }
            }
        }
        dA[i] = best;   // == i iff local min (basin root)
    }
    __syncthreads();

    // ---- pointer jumping: ping-pong doubling with exact early exit (R11) ----
    int* rootArr = dA;
    {
        int* src = dA;
        int* dst = dB;
        for (int pass = 0; pass < JMAXP; ++pass) {
            bool changed = false;
            for (int i = tid; i < M; i += NTH) {
                int q0 = src[i];
                int q1 = src[q0];
                dst[i] = q1;
                changed |= (q1 != q0);
            }
            unsigned long long mk = __ballot(changed);
            if (lane == 0 && mk) atomicOr(&jflag[pass], 1);
            __syncthreads();
            rootArr = dst;
            if (!jflag[pass]) break;
            int* tmp = src; src = dst; dst = tmp;
        }
    }
    int* cidmap = (rootArr == dA) ? dB : dA;   // scratch that won't clobber rootArr

    // ---- collect basin roots (per-wave ballot + one atomic per wave) ----
    for (int it = 0; it < 2; ++it) {
        int i = it * NTH + tid;
        bool isr = (i < M) && (rootArr[i] == i);
        unsigned long long mk = __ballot(isr);
        int base = 0;
        if (lane == 0) base = atomicAdd(&bcnt, __popcll(mk));
        base = __shfl(base, 0, 64);
        int pre = __popcll(mk & ((1ull << lane) - 1ull));
        if (isr && (base + pre) < BCAP)
            rootsU[base + pre] = ((unsigned long long)f2mono(vals[i]) << 32) | (unsigned)i;
    }
    __syncthreads();
    int B = bcnt; if (B > BCAP) B = BCAP;
    const int B64 = (B + 63) & ~63;
    for (int i = B + tid; i < B64; i += NTH) rootsU[i] = ~0ull;
    __syncthreads();

    // ---- cid = value rank of root (rank-by-count) ----
    for (int i = tid; i < B64; i += NTH) {
        unsigned long long ki = rootsU[i];
        int rk = rankOf(rootsU, B64, ki);
        if (i < B) {
            int cell = (int)(ki & 0xFFFFFFFFull);
            cidmap[cell] = rk;
            bval[rk] = (unsigned)(ki >> 32);
        }
    }
    __syncthreads();
    for (int i = tid; i < M; i += NTH) cido[i] = cidmap[rootArr[i]];
    __syncthreads();

    // ---- cross-basin edges -> hash dedup (min weight per basin pair) ----
    for (int c = tid; c < NPIX; c += NTH) {
        float vc = vals[c];
        int bc = cido[c];
        int nb[8];
        int K = get_nbrs(c, which, nb);
        unsigned wm = f2mono(vc);
        for (int k = 0; k < K; ++k) {
            int n = nb[k]; if (n < 0) continue;
            float vn = vals[n];
            if (!(vn < vc || (vn == vc && n < c))) continue;  // emit from higher endpoint
            int bn = cido[n];
            if (bn == bc) continue;
            unsigned c0 = (unsigned)(bc < bn ? bc : bn);
            unsigned c1 = (unsigned)(bc < bn ? bn : bc);
            unsigned pk  = (c0 << 9) | c1;       // cids < 512 -> 18 bits
            unsigned key = pk + 1u;
            unsigned slot = (pk * 0x9E3779B1u) >> 21;  // 11-bit hash
            for (;;) {
                unsigned prev = atomicCAS(&hkey[slot], 0u, key);
                if (prev == 0u || prev == key) { atomicMin(&hval[slot], wm); break; }
                slot = (slot + 1) & HMASK;
            }
        }
    }
    __syncthreads();

    // ---- gather survivors (per-wave ballot + one atomic per wave) ----
    for (int it = 0; it < HSZ / NTH; ++it) {
        int i = it * NTH + tid;
        unsigned key = hkey[i];
        bool sv = key != 0u;
        unsigned long long mk = __ballot(sv);
        int base = 0;
        if (lane == 0) base = atomicAdd(&scnt, __popcll(mk));
        base = __shfl(base, 0, 64);
        int pre = __popcll(mk & ((1ull << lane) - 1ull));
        if (sv)
            e2[base + pre] = ((unsigned long long)hval[i] << 18)
                           | (unsigned long long)(key - 1u);
    }
    __syncthreads();
    const int S = scnt;                          // <= HSZ = ECAP, no overflow
    const int S64 = (S + 63) & ~63;
    for (int i = S + tid; i < S64; i += NTH) { e2[i] = ~0ull; e3[i] = ~0ull; }
    __syncthreads();

    // ---- weight-sort edges by rank-by-count scatter into e3 ----
    for (int i = tid; i < S64; i += NTH) {
        unsigned long long ki = e2[i];
        int rk = rankOf(e2, S64, ki);
        if (i < S) e3[rk] = ki;
    }
    __syncthreads();

    // ---- serial Kruskal on wave 0: 4-wide speculative, regs + SALU resolve ----
    // BRANCHLESS record+relabel: no per-edge scalar branches. Non-merge edges
    // relabel with ys[t]=-1 (matches no label -> no-op) and record into the
    // dump slot mrec[PCAP].
    auto kruskal = [&](auto icreg) {
        constexpr int NREG = decltype(icreg)::v;
        int lab[NREG];
        #pragma unroll
        for (int r = 0; r < NREG; ++r) lab[r] = r * 64 + tid;
        int np = 0;
        const int S4 = (S + 3) & ~3;
        unsigned long long ecache = 0ull;
        for (int base = 0; base < S4; base += 4) {
            if ((base & 63) == 0) ecache = e3[base + tid];   // base mult of 64, tid<64
            unsigned klo[4];
            int la[4], lb[4];
            #pragma unroll
            for (int t = 0; t < 4; ++t) {
                int ln = (base & 63) + t;
                klo[t] = (unsigned)__builtin_amdgcn_readlane((int)(unsigned)ecache, ln);
                unsigned pk  = klo[t] & 0x3FFFFu;
                unsigned raa = pk >> 9, rbb = pk & 511u;
                int sa = (int)(raa >> 6), sb = (int)(rbb >> 6);
                asm volatile("" : "+v"(sa), "+v"(sb));   // force cndmask tree
                int g1, g2;
                if constexpr (NREG == 2) {
                    g1 = (sa & 1) ? lab[1] : lab[0];
                    g2 = (sb & 1) ? lab[1] : lab[0];
                } else if constexpr (NREG == 4) {
                    int a1 = (sa & 1) ? lab[1] : lab[0];
                    int b1 = (sa & 1) ? lab[3] : lab[2];
                    g1 = (sa & 2) ? b1 : a1;
                    int a2 = (sb & 1) ? lab[1] : lab[0];
                    int b2 = (sb & 1) ? lab[3] : lab[2];
                    g2 = (sb & 2) ? b2 : a2;
                } else {
                    int a1 = (sa & 1) ? lab[1] : lab[0];
                    int b1 = (sa & 1) ? lab[3] : lab[2];
                    int c1 = (sa & 1) ? lab[5] : lab[4];
                    int d1 = (sa & 1) ? lab[7] : lab[6];
                    int e1 = (sa & 2) ? b1 : a1;
                    int f1 = (sa & 2) ? d1 : c1;
                    g1 = (sa & 4) ? f1 : e1;
                    int a2 = (sb & 1) ? lab[1] : lab[0];
                    int b2 = (sb & 1) ? lab[3] : lab[2];
                    int c2 = (sb & 1) ? lab[5] : lab[4];
                    int d2 = (sb & 1) ? lab[7] : lab[6];
                    int e2v = (sb & 2) ? b2 : a2;
                    int f2 = (sb & 2) ? d2 : c2;
                    g2 = (sb & 4) ? f2 : e2v;
                }
                la[t] = __builtin_amdgcn_readlane(g1, (int)(raa & 63u));
                lb[t] = __builtin_amdgcn_readlane(g2, (int)(rbb & 63u));
            }
            // sequential resolve with cascading fix-ups (SALU; uniform values)
            int ys[4], es[4];
            #pragma unroll
            for (int t = 0; t < 4; ++t) {
                int A = la[t], Bv = lb[t];
                #pragma unroll
                for (int k = 0; k < t; ++k) {
                    A  = (A  == ys[k]) ? es[k] : A;
                    Bv = (Bv == ys[k]) ? es[k] : Bv;
                }
                int mn = A < Bv ? A : Bv;
                int mx = A ^ Bv ^ mn;
                es[t] = mn;
                ys[t] = (A != Bv) ? mx : -1;
            }
            // branchless record + relabel
            #pragma unroll
            for (int t = 0; t < 4; ++t) {
                bool mg = ys[t] >= 0;
                unsigned khit = (unsigned)__builtin_amdgcn_readlane(
                    (int)(unsigned)(ecache >> 32), (base & 63) + t);
                unsigned w = (klo[t] >> 18) | (khit << 14);
                int idx = (mg && np < PCAP) ? np : PCAP;    // dump slot when no merge
                if (tid == 0)
                    mrec[idx] = ((unsigned long long)w << 32) | (unsigned)(mg ? ys[t] : 0);
                np += mg ? 1 : 0;
                #pragma unroll
                for (int r = 0; r < NREG; ++r)              // ys[t]=-1 matches nothing
                    lab[r] = (lab[r] == ys[t]) ? es[t] : lab[r];
            }
        }
        if (tid == 0) npairs = (np < PCAP) ? np : PCAP;
    };
    if (tid < 64 && S > 0) {
        if (B <= 128)      kruskal(IC<2>{});
        else if (B <= 256) kruskal(IC<4>{});
        else               kruskal(IC<8>{});
    }
    __syncthreads();
    const int P = npairs;
    const int P64 = (P + 63) & ~63;

    // ---- materialize pairs + build selection keys (pers desc, idx asc) ----
    for (int i = tid; i < P64; i += NTH) {
        unsigned long long kk2 = ~0ull;
        if (i < P) {
            unsigned long long m = mrec[i];
            int y = (int)(m & 0xFFFFFFFFull);
            float w  = mono2f((unsigned)(m >> 32));
            float bf = mono2f(bval[y]);
            float b, d;
            if (which == 0) { b = bf; d = w; }
            else            { b = -w; d = -bf; }
            pb[i] = b; pdd[i] = d;
            unsigned pm = __float_as_uint(d - b);   // pers > 0 -> monotone bits
            kk2 = ((unsigned long long)(~pm) << 32) | (unsigned)i;
        }
        e2[i] = kk2;
    }
    if (tid < NMAXP) rsel[tid] = -1;
    __syncthreads();

    // ---- top-NMAXP by rank-by-count ----
    const int off = (which == 0) ? 1 : 0;          // H0 slot 0 = essential pair
    for (int i = tid; i < P64; i += NTH) {
        unsigned long long ki = e2[i];
        int rk = rankOf(e2, P64, ki);
        if (i < P && rk < NMAXP - off) rsel[rk + off] = i;
    }
    __syncthreads();

    // ---- write diagram: [32, 2, 100, 2] ----
    float* o = out + (size_t)blk * NMAXP * 2;
    if (tid < NMAXP) {
        float b = 0.f, d = 0.f;
        if (which == 0 && tid == 0) { b = mono2f(bval[0]); d = ESS_DEATH; }
        else {
            int q = rsel[tid];
            if (q >= 0) { b = pb[q]; d = pdd[q]; }
        }
        o[tid * 2]     = b;
        o[tid * 2 + 1] = d;
    }
}

extern "C" void kernel_launch(void* const* d_in, const int* in_sizes, int n_in,
                              void* d_out, int out_size, void* d_ws, size_t ws_size,
                              hipStream_t stream) {
    (void)in_sizes; (void)n_in; (void)out_size; (void)d_ws; (void)ws_size;
    const float* x = (const float*)d_in[0];
    float* out = (float*)d_out;
    pd_kernel<<<dim3(64), dim3(NTH), 0, stream>>>(x, out);
}

// Round 15
// 126.283 us; speedup vs baseline: 1.1467x; 1.1467x over previous
//
#include <hip/hip_runtime.h>
#include <math.h>

#define HH 28
#define WW 28
#define NPIX 784
#define MMAX 785
#define NMAXP 100
#define NTH 512
#define BCAP 512       // max basins (theory bound: H1 4-conn <= 393)
#define HSZ 2048
#define HMASK 2047
#define ECAP 2048      // deduped basin-pair edges (random ~470); max survivors = HSZ
#define PCAP 512
#define JMAXP 10       // 2^10 >= 785 worst-case descent depth
// Essential-death sentinel: must stay FINITE after the harness's bf16
// round-trip (FLT_MAX rounds to +inf in bf16 -> inf-inf=NaN). 1e30 is safe.
#define ESS_DEATH 1e30f

template<int N> struct IC { static constexpr int v = N; };

// monotone float<->u32 (totally ordered as unsigned)
__device__ __forceinline__ unsigned f2mono(float f) {
    unsigned u = __float_as_uint(f);
    return (u & 0x80000000u) ? ~u : (u | 0x80000000u);
}
__device__ __forceinline__ float mono2f(unsigned m) {
    unsigned u = (m & 0x80000000u) ? (m ^ 0x80000000u) : ~m;
    return __uint_as_float(u);
}

// neighbors of cell c; nb[k] = -1 if invalid.
// which==0: 8-conn. which==1: 4-conn + virtual boundary node NPIX.
__device__ __forceinline__ int get_nbrs(int c, int which, int* nb) {
    int ci = c / WW;
    int cj = c - ci * WW;
    if (which == 0) {
        const int di[8] = {-1,-1,-1, 0, 0, 1, 1, 1};
        const int dj[8] = {-1, 0, 1,-1, 1,-1, 0, 1};
        #pragma unroll
        for (int k = 0; k < 8; ++k) {
            int ii = ci + di[k], jj = cj + dj[k];
            nb[k] = (ii >= 0 && ii < HH && jj >= 0 && jj < WW) ? (ii * WW + jj) : -1;
        }
        return 8;
    } else {
        const int di[4] = {-1, 1, 0, 0};
        const int dj[4] = { 0, 0,-1, 1};
        #pragma unroll
        for (int k = 0; k < 4; ++k) {
            int ii = ci + di[k], jj = cj + dj[k];
            nb[k] = (ii >= 0 && ii < HH && jj >= 0 && jj < WW) ? (ii * WW + jj) : -1;
        }
        nb[4] = (ci == 0 || ci == HH - 1 || cj == 0 || cj == WW - 1) ? NPIX : -1;
        return 5;
    }
}

// One block per (sample, dim): blk = s*2 + which.
// which==0 -> H0 (8-conn sublevel on x); which==1 -> H1 via superlevel
// (sublevel on -x, 4-conn, virtual -inf boundary node).
__global__ __launch_bounds__(NTH)
void pd_kernel(const float* __restrict__ x, float* __restrict__ out)
{
    const int blk   = blockIdx.x;
    const int s     = blk >> 1;
    const int which = blk & 1;
    const int tid   = threadIdx.x;
    const int lane  = tid & 63;
    const int M     = NPIX + which;

    __shared__ float vals[MMAX];
    __shared__ int   dA[MMAX];                  // steepest-descent pointer (ping)
    __shared__ int   dB[MMAX];                  // pointer (pong)
    __shared__ int   cido[MMAX];                // per-cell compact basin id
    __shared__ unsigned long long rootsU[BCAP]; // unsorted (valmono<<32)|cell, 64-padded
    __shared__ unsigned bval[BCAP];             // basin-min valmono per cid (= value rank)
    __shared__ unsigned hkey[HSZ];              // hash: pk+1 (0 = empty)
    __shared__ unsigned hval[HSZ];              // hash: min weight (monotone u32)
    __shared__ unsigned long long e2[ECAP];     // unsorted (wmono<<18)|pk; later sel keys
    __shared__ unsigned long long e3[ECAP];     // rank-scattered edges (weight order)
    __shared__ unsigned long long mrec[PCAP];   // raw merge records (wmono<<32)|y
    __shared__ float pb[PCAP], pdd[PCAP];       // recorded pairs (output space)
    __shared__ int   rsel[NMAXP];               // output slot -> pair index
    __shared__ int   bcnt, scnt, npairs;
    __shared__ int   jflag[JMAXP + 1];

    // rank of ki among arr[0..N64) (N64 = 64-multiple, padded with ~0ull;
    // distinct keys). Chunked: wave loads 64 keys coalesced, broadcasts via
    // readlane (unrolled -> constant lane), counts kjj < ki. No barriers.
    auto rankOf = [&](const unsigned long long* arr, int N64,
                      unsigned long long ki) -> int {
        int rk = 0;
        for (int base = 0; base < N64; base += 64) {
            unsigned long long kj = arr[base + lane];
            unsigned lo = (unsigned)kj, hi = (unsigned)(kj >> 32);
            #pragma unroll
            for (int t = 0; t < 64; ++t) {
                unsigned jlo = (unsigned)__builtin_amdgcn_readlane((int)lo, t);
                unsigned jhi = (unsigned)__builtin_amdgcn_readlane((int)hi, t);
                unsigned long long kjj = ((unsigned long long)jhi << 32) | jlo;
                rk += (kjj < ki) ? 1 : 0;
            }
        }
        return rk;
    };

    if (tid == 0) { bcnt = 0; scnt = 0; npairs = 0; }
    if (tid < JMAXP + 1) jflag[tid] = 0;
    for (int i = tid; i < HSZ; i += NTH) { hkey[i] = 0u; hval[i] = 0xFFFFFFFFu; }
    for (int i = tid; i < NPIX; i += NTH) {
        float v = x[s * NPIX + i];
        vals[i] = which ? -v : v;
    }
    if (tid == 0 && which) vals[NPIX] = -INFINITY;
    __syncthreads();

    // ---- steepest-descent pointer: lex-min (val, idx) over {self} U nbrs ----
    for (int i = tid; i < M; i += NTH) {
        int best = i; float bv = vals[i];
        if (i < NPIX) {
            int nb[8];
            int K = get_nbrs(i, which, nb);
            for (int k = 0; k < K; ++k) {
                int n = nb[k]; if (n < 0) continue;
                float vn = vals[n];
                if (vn < bv || (vn == bv && n < best)) { bv = vn; best = n; }
            }
        }
        dA[i] = best;   // == i iff local min (basin root)
    }
    __syncthreads();

    // ---- pointer jumping: ping-pong doubling with exact early exit (R11) ----
    int* rootArr = dA;
    {
        int* src = dA;
        int* dst = dB;
        for (int pass = 0; pass < JMAXP; ++pass) {
            bool changed = false;
            for (int i = tid; i < M; i += NTH) {
                int q0 = src[i];
                int q1 = src[q0];
                dst[i] = q1;
                changed |= (q1 != q0);
            }
            unsigned long long mk = __ballot(changed);
            if (lane == 0 && mk) atomicOr(&jflag[pass], 1);
            __syncthreads();
            rootArr = dst;
            if (!jflag[pass]) break;
            int* tmp = src; src = dst; dst = tmp;
        }
    }
    int* cidmap = (rootArr == dA) ? dB : dA;   // scratch that won't clobber rootArr

    // ---- collect basin roots (per-wave ballot + one atomic per wave) ----
    for (int it = 0; it < 2; ++it) {
        int i = it * NTH + tid;
        bool isr = (i < M) && (rootArr[i] == i);
        unsigned long long mk = __ballot(isr);
        int base = 0;
        if (lane == 0) base = atomicAdd(&bcnt, __popcll(mk));
        base = __shfl(base, 0, 64);
        int pre = __popcll(mk & ((1ull << lane) - 1ull));
        if (isr && (base + pre) < BCAP)
            rootsU[base + pre] = ((unsigned long long)f2mono(vals[i]) << 32) | (unsigned)i;
    }
    __syncthreads();
    int B = bcnt; if (B > BCAP) B = BCAP;
    const int B64 = (B + 63) & ~63;
    for (int i = B + tid; i < B64; i += NTH) rootsU[i] = ~0ull;
    __syncthreads();

    // ---- cid = value rank of root (rank-by-count) ----
    for (int i = tid; i < B64; i += NTH) {
        unsigned long long ki = rootsU[i];
        int rk = rankOf(rootsU, B64, ki);
        if (i < B) {
            int cell = (int)(ki & 0xFFFFFFFFull);
            cidmap[cell] = rk;
            bval[rk] = (unsigned)(ki >> 32);
        }
    }
    __syncthreads();
    for (int i = tid; i < M; i += NTH) cido[i] = cidmap[rootArr[i]];
    __syncthreads();

    // ---- cross-basin edges -> hash dedup (min weight per basin pair) ----
    for (int c = tid; c < NPIX; c += NTH) {
        float vc = vals[c];
        int bc = cido[c];
        int nb[8];
        int K = get_nbrs(c, which, nb);
        unsigned wm = f2mono(vc);
        for (int k = 0; k < K; ++k) {
            int n = nb[k]; if (n < 0) continue;
            float vn = vals[n];
            if (!(vn < vc || (vn == vc && n < c))) continue;  // emit from higher endpoint
            int bn = cido[n];
            if (bn == bc) continue;
            unsigned c0 = (unsigned)(bc < bn ? bc : bn);
            unsigned c1 = (unsigned)(bc < bn ? bn : bc);
            unsigned pk  = (c0 << 9) | c1;       // cids < 512 -> 18 bits
            unsigned key = pk + 1u;
            unsigned slot = (pk * 0x9E3779B1u) >> 21;  // 11-bit hash
            for (;;) {
                unsigned prev = atomicCAS(&hkey[slot], 0u, key);
                if (prev == 0u || prev == key) { atomicMin(&hval[slot], wm); break; }
                slot = (slot + 1) & HMASK;
            }
        }
    }
    __syncthreads();

    // ---- gather survivors (per-wave ballot + one atomic per wave) ----
    for (int it = 0; it < HSZ / NTH; ++it) {
        int i = it * NTH + tid;
        unsigned key = hkey[i];
        bool sv = key != 0u;
        unsigned long long mk = __ballot(sv);
        int base = 0;
        if (lane == 0) base = atomicAdd(&scnt, __popcll(mk));
        base = __shfl(base, 0, 64);
        int pre = __popcll(mk & ((1ull << lane) - 1ull));
        if (sv)
            e2[base + pre] = ((unsigned long long)hval[i] << 18)
                           | (unsigned long long)(key - 1u);
    }
    __syncthreads();
    const int S = scnt;                          // <= HSZ = ECAP, no overflow
    const int S64 = (S + 63) & ~63;
    for (int i = S + tid; i < S64; i += NTH) { e2[i] = ~0ull; e3[i] = ~0ull; }
    __syncthreads();

    // ---- weight-sort edges by rank-by-count scatter into e3 ----
    for (int i = tid; i < S64; i += NTH) {
        unsigned long long ki = e2[i];
        int rk = rankOf(e2, S64, ki);
        if (i < S) e3[rk] = ki;
    }
    __syncthreads();

    // ---- serial Kruskal on wave 0 (R9/R11): 4-wide speculative, regs + SALU ----
    auto kruskal = [&](auto icreg) {
        constexpr int NREG = decltype(icreg)::v;
        int lab[NREG];
        #pragma unroll
        for (int r = 0; r < NREG; ++r) lab[r] = r * 64 + tid;
        int np = 0;
        const int S4 = (S + 3) & ~3;
        unsigned long long ecache = 0ull;
        for (int base = 0; base < S4; base += 4) {
            if ((base & 63) == 0) ecache = e3[base + tid];   // base mult of 64, tid<64
            unsigned klo[4];
            int la[4], lb[4];
            #pragma unroll
            for (int t = 0; t < 4; ++t) {
                int ln = (base & 63) + t;
                klo[t] = (unsigned)__builtin_amdgcn_readlane((int)(unsigned)ecache, ln);
                unsigned pk  = klo[t] & 0x3FFFFu;
                unsigned raa = pk >> 9, rbb = pk & 511u;
                int sa = (int)(raa >> 6), sb = (int)(rbb >> 6);
                asm volatile("" : "+v"(sa), "+v"(sb));   // force cndmask tree
                int g1, g2;
                if constexpr (NREG == 2) {
                    g1 = (sa & 1) ? lab[1] : lab[0];
                    g2 = (sb & 1) ? lab[1] : lab[0];
                } else if constexpr (NREG == 4) {
                    int a1 = (sa & 1) ? lab[1] : lab[0];
                    int b1 = (sa & 1) ? lab[3] : lab[2];
                    g1 = (sa & 2) ? b1 : a1;
                    int a2 = (sb & 1) ? lab[1] : lab[0];
                    int b2 = (sb & 1) ? lab[3] : lab[2];
                    g2 = (sb & 2) ? b2 : a2;
                } else {
                    int a1 = (sa & 1) ? lab[1] : lab[0];
                    int b1 = (sa & 1) ? lab[3] : lab[2];
                    int c1 = (sa & 1) ? lab[5] : lab[4];
                    int d1 = (sa & 1) ? lab[7] : lab[6];
                    int e1 = (sa & 2) ? b1 : a1;
                    int f1 = (sa & 2) ? d1 : c1;
                    g1 = (sa & 4) ? f1 : e1;
                    int a2 = (sb & 1) ? lab[1] : lab[0];
                    int b2 = (sb & 1) ? lab[3] : lab[2];
                    int c2 = (sb & 1) ? lab[5] : lab[4];
                    int d2 = (sb & 1) ? lab[7] : lab[6];
                    int e2v = (sb & 2) ? b2 : a2;
                    int f2 = (sb & 2) ? d2 : c2;
                    g2 = (sb & 4) ? f2 : e2v;
                }
                la[t] = __builtin_amdgcn_readlane(g1, (int)(raa & 63u));
                lb[t] = __builtin_amdgcn_readlane(g2, (int)(rbb & 63u));
            }
            int ys[4], es[4];
            #pragma unroll
            for (int t = 0; t < 4; ++t) {
                int A = la[t], Bv = lb[t];
                #pragma unroll
                for (int k = 0; k < t; ++k) {
                    A  = (A  == ys[k]) ? es[k] : A;
                    Bv = (Bv == ys[k]) ? es[k] : Bv;
                }
                int mn = A < Bv ? A : Bv;
                int mx = A ^ Bv ^ mn;
                es[t] = mn;
                ys[t] = (A != Bv) ? mx : -1;
            }
            #pragma unroll
            for (int t = 0; t < 4; ++t) {
                if (ys[t] >= 0) {
                    unsigned khit = (unsigned)__builtin_amdgcn_readlane(
                        (int)(unsigned)(ecache >> 32), (base & 63) + t);
                    unsigned w = (klo[t] >> 18) | (khit << 14);
                    if (tid == 0 && np < PCAP)
                        mrec[np] = ((unsigned long long)w << 32) | (unsigned)ys[t];
                    ++np;
                    #pragma unroll
                    for (int r = 0; r < NREG; ++r)
                        lab[r] = (lab[r] == ys[t]) ? es[t] : lab[r];
                }
            }
        }
        if (tid == 0) npairs = (np < PCAP) ? np : PCAP;
    };
    if (tid < 64 && S > 0) {
        if (B <= 128)      kruskal(IC<2>{});
        else if (B <= 256) kruskal(IC<4>{});
        else               kruskal(IC<8>{});
    }
    __syncthreads();
    const int P = npairs;
    const int P64 = (P + 63) & ~63;

    // ---- materialize pairs + build selection keys (pers desc, idx asc) ----
    for (int i = tid; i < P64; i += NTH) {
        unsigned long long kk2 = ~0ull;
        if (i < P) {
            unsigned long long m = mrec[i];
            int y = (int)(m & 0xFFFFFFFFull);
            float w  = mono2f((unsigned)(m >> 32));
            float bf = mono2f(bval[y]);
            float b, d;
            if (which == 0) { b = bf; d = w; }
            else            { b = -w; d = -bf; }
            pb[i] = b; pdd[i] = d;
            unsigned pm = __float_as_uint(d - b);   // pers > 0 -> monotone bits
            kk2 = ((unsigned long long)(~pm) << 32) | (unsigned)i;
        }
        e2[i] = kk2;
    }
    if (tid < NMAXP) rsel[tid] = -1;
    __syncthreads();

    // ---- top-NMAXP by rank-by-count ----
    const int off = (which == 0) ? 1 : 0;          // H0 slot 0 = essential pair
    for (int i = tid; i < P64; i += NTH) {
        unsigned long long ki = e2[i];
        int rk = rankOf(e2, P64, ki);
        if (i < P && rk < NMAXP - off) rsel[rk + off] = i;
    }
    __syncthreads();

    // ---- write diagram: [32, 2, 100, 2] ----
    float* o = out + (size_t)blk * NMAXP * 2;
    if (tid < NMAXP) {
        float b = 0.f, d = 0.f;
        if (which == 0 && tid == 0) { b = mono2f(bval[0]); d = ESS_DEATH; }
        else {
            int q = rsel[tid];
            if (q >= 0) { b = pb[q]; d = pdd[q]; }
        }
        o[tid * 2]     = b;
        o[tid * 2 + 1] = d;
    }
}

extern "C" void kernel_launch(void* const* d_in, const int* in_sizes, int n_in,
                              void* d_out, int out_size, void* d_ws, size_t ws_size,
                              hipStream_t stream) {
    (void)in_sizes; (void)n_in; (void)out_size; (void)d_ws; (void)ws_size;
    const float* x = (const float*)d_in[0];
    float* out = (float*)d_out;
    pd_kernel<<<dim3(64), dim3(NTH), 0, stream>>>(x, out);
}